// Round 1
// baseline (194.787 us; speedup 1.0000x reference)
//
#include <hip/hip_runtime.h>
#include <hip/hip_fp16.h>

// Fused 3-layer ReLU-RNN + linear head, MI355X (gfx950).
// T=512, B=4096, IN=4, H1=24, H2=48, H3=24, OUT=2.
//
// Strategy: one wave (64 threads) owns 16 batch columns for the entire
// 512-step recurrence. Batch = MFMA N dim (col = lane&15), neurons = M dim.
// Weights are pre-packed once into per-lane A-fragments (held in VGPRs for
// the whole kernel); biases enter as the MFMA C operand. Layer outputs (D,
// layout col=lane&15, row=4*(lane>>4)+reg — HW-verified) convert IN-LANE
// (relu + f16 pack) into the next layer's B fragment under the consistent
// k = 4q+j half-fragment convention; since A and B are filled with the SAME
// slot->k convention, the contraction is invariant to the HW's true k order.
// Zero LDS, zero barriers, grid = 256 blocks (1 per CU).

#define TSEQ 512
#define NBAT 4096

typedef float    f32x4 __attribute__((ext_vector_type(4)));
typedef _Float16 f16x8 __attribute__((ext_vector_type(8)));

union BFrag { f16x8 h; unsigned u[4]; };

__device__ __forceinline__ f32x4 MF(f16x8 a, f16x8 b, f32x4 c) {
  return __builtin_amdgcn_mfma_f32_16x16x32_f16(a, b, c, 0, 0, 0);
}

__device__ __forceinline__ unsigned pkh(float a, float b) {
  union { __half2 h2; unsigned u; } x;
  x.h2 = __floats2half2_rn(a, b);
  return x.u;
}
__device__ __forceinline__ unsigned pkr(float a, float b) {
  return pkh(fmaxf(a, 0.f), fmaxf(b, 0.f));
}

struct WP {
  const float *wih0, *whh0, *wih1, *whh1, *wih2, *whh2, *wout;
};

// Concatenated-weight view per layer, zero-padded so garbage B slots
// always multiply by 0.
//  L0 (K=32): k<24 -> W_hh0[m][k]          (h1_prev), k in [28,32) -> W_ih0[m][k-28] (x_t)
//  L1 (K=96): k<24 -> W_ih1[m][k] (a1),    k in [32,80) -> W_hh1[m][k-32] (h2_prev)
//  L2 (K=96): k<48 -> W_ih2[m][k] (a2),    k in [48,72) -> W_hh2[m][k-48] (h3_prev)
//  L3 (K=32): k<24 -> W_out[m][k] (a3), m<2
__device__ float wcat(int layer, int m, int k, const WP& P) {
  if (layer == 0) {
    if (m < 24) {
      if (k < 24) return P.whh0[m * 24 + k];
      if (k >= 28 && k < 32) return P.wih0[m * 4 + (k - 28)];
    }
    return 0.f;
  } else if (layer == 1) {
    if (m < 48) {
      if (k < 24) return P.wih1[m * 24 + k];
      if (k >= 32 && k < 80) return P.whh1[m * 48 + (k - 32)];
    }
    return 0.f;
  } else if (layer == 2) {
    if (m < 24) {
      if (k < 48) return P.wih2[m * 48 + k];
      if (k >= 48 && k < 72) return P.whh2[m * 24 + (k - 48)];
    }
    return 0.f;
  } else {
    if (m < 2 && k < 24) return P.wout[m * 24 + k];
    return 0.f;
  }
}

// A fragment (16x16x32 f16): lane holds row m = 16*mt + (lane&15),
// slots j<4: k = kc*32 + 4q + j ; slots j>=4: k = kc*32 + 16 + 4q + (j-4).
__device__ f16x8 afrag(int layer, int mt, int kc, const WP& P) {
  int m  = mt * 16 + (threadIdx.x & 15);
  int kb = kc * 32 + 4 * ((threadIdx.x >> 4) & 3);
  f16x8 r;
#pragma unroll
  for (int j = 0; j < 4; ++j) r[j] = (_Float16)wcat(layer, m, kb + j, P);
#pragma unroll
  for (int j = 0; j < 4; ++j) r[4 + j] = (_Float16)wcat(layer, m, kb + 16 + j, P);
  return r;
}

// Bias as C operand: reg i holds bias for neuron m = 16*mt + 4q + i.
__device__ f32x4 cfrag(const float* b1, const float* b2, int mt, int nvalid) {
  int q = (threadIdx.x >> 4) & 3;
  f32x4 r;
#pragma unroll
  for (int i = 0; i < 4; ++i) {
    int m = mt * 16 + 4 * q + i;
    float v = 0.f;
    if (m < nvalid) { v = b1[m]; if (b2) v += b2[m]; }
    r[i] = v;
  }
  return r;
}

__global__ void __launch_bounds__(64)
rnn3_fused(const float* __restrict__ x,
           const float* __restrict__ wih0, const float* __restrict__ whh0,
           const float* __restrict__ bih0, const float* __restrict__ bhh0,
           const float* __restrict__ wih1, const float* __restrict__ whh1,
           const float* __restrict__ bih1, const float* __restrict__ bhh1,
           const float* __restrict__ wih2, const float* __restrict__ whh2,
           const float* __restrict__ bih2, const float* __restrict__ bhh2,
           const float* __restrict__ wout, const float* __restrict__ bout,
           float* __restrict__ out) {
  const int lane = threadIdx.x;
  const int c = lane & 15;        // batch column within tile
  const int q = lane >> 4;        // lane quadrant
  const int b0 = blockIdx.x * 16; // batch tile base

  WP P{wih0, whh0, wih1, whh1, wih2, whh2, wout};

  // ---- persistent A fragments (weights) ----
  f16x8 A00 = afrag(0, 0, 0, P);
  f16x8 A01 = afrag(0, 1, 0, P);
  f16x8 A1[3][3];
#pragma unroll
  for (int mt = 0; mt < 3; ++mt)
#pragma unroll
    for (int kc = 0; kc < 3; ++kc) A1[mt][kc] = afrag(1, mt, kc, P);
  f16x8 A2[2][3];
#pragma unroll
  for (int mt = 0; mt < 2; ++mt)
#pragma unroll
    for (int kc = 0; kc < 3; ++kc) A2[mt][kc] = afrag(2, mt, kc, P);
  f16x8 A3 = afrag(3, 0, 0, P);

  // ---- bias fragments ----
  f32x4 C00 = cfrag(bih0, bhh0, 0, 24);
  f32x4 C01 = cfrag(bih0, bhh0, 1, 24);
  f32x4 C10 = cfrag(bih1, bhh1, 0, 48);
  f32x4 C11 = cfrag(bih1, bhh1, 1, 48);
  f32x4 C12 = cfrag(bih1, bhh1, 2, 48);
  f32x4 C20 = cfrag(bih2, bhh2, 0, 24);
  f32x4 C21 = cfrag(bih2, bhh2, 1, 24);
  f32x4 C3  = cfrag(bout, nullptr, 0, 2);

  const float4* x4 = (const float4*)x;   // x[t][b][0..3] -> index t*NBAT+b
  float2*       o2 = (float2*)out;       // out[t][b][0..1] -> index t*NBAT+b

  // ---- loop-carried B fragments ----
  // FA: [h1(t-1) tiles | q==3: x_t]   (L0 chunk0; also L1 chunk0 after rebuild)
  // FB: [h2 t0 | h2 t1]               (L1 chunk1 / L2 chunk0)
  // FC: [h2 t2 | h3_prev t0]          (L1 chunk2 / L2 chunk1)
  // FD: [h3 t0 | h3 t1]               (out chunk0; feeds next FC/BE)
  BFrag FA, FB, FC, FD;
  {
    float4 xv0 = x4[(size_t)b0 + c];  // x_0
    FA.u[0] = 0u; FA.u[1] = 0u;
    FA.u[2] = (q == 3) ? pkh(xv0.x, xv0.y) : 0u;
    FA.u[3] = (q == 3) ? pkh(xv0.z, xv0.w) : 0u;
    FB.u[0] = FB.u[1] = FB.u[2] = FB.u[3] = 0u;
    FC.u[0] = FC.u[1] = FC.u[2] = FC.u[3] = 0u;
    FD.u[0] = FD.u[1] = FD.u[2] = FD.u[3] = 0u;
  }
  // x pipeline: xcur = x_{t+1} (consumed building FA at step t), loaded 2 ahead.
  float4 xcur = x4[(size_t)NBAT + b0 + c];  // x_1

#pragma unroll 1
  for (int t = 0; t < TSEQ; ++t) {
    int tn = (t + 2 < TSEQ) ? t + 2 : TSEQ - 1;
    float4 xnxt = x4[(size_t)tn * NBAT + b0 + c];  // issue early, used next iter

    // ---- L0: h1 = relu(Wcat0 . [h1_prev ; x_t] + b) ----
    f32x4 a10 = MF(A00, FA.h, C00);
    f32x4 a11 = MF(A01, FA.h, C01);

    // ---- L1 partial: chunks with last-step data first ----
    f32x4 a2_0 = MF(A1[0][1], FB.h, C10);
    f32x4 a2_1 = MF(A1[1][1], FB.h, C11);
    f32x4 a2_2 = MF(A1[2][1], FB.h, C12);
    a2_0 = MF(A1[0][2], FC.h, a2_0);
    a2_1 = MF(A1[1][2], FC.h, a2_1);
    a2_2 = MF(A1[2][2], FC.h, a2_2);

    // ---- build FA_new = [h1_new | x_{t+1} in q3] ----
    unsigned h1b = pkr(a11[0], a11[1]);
    unsigned h1c = pkr(a11[2], a11[3]);
    FA.u[0] = pkr(a10[0], a10[1]);
    FA.u[1] = pkr(a10[2], a10[3]);
    FA.u[2] = (q == 3) ? pkh(xcur.x, xcur.y) : h1b;
    FA.u[3] = (q == 3) ? pkh(xcur.z, xcur.w) : h1c;

    // ---- L1 finish: chunk0 (a1 = h1_new; x slots hit zero W columns) ----
    a2_0 = MF(A1[0][0], FA.h, a2_0);
    a2_1 = MF(A1[1][0], FA.h, a2_1);
    a2_2 = MF(A1[2][0], FA.h, a2_2);

    // ---- L2 partial: chunk2 uses h3_prev t1 (from FD old) ----
    BFrag BE;
    BE.u[0] = FD.u[2]; BE.u[1] = FD.u[3]; BE.u[2] = 0u; BE.u[3] = 0u;
    f32x4 a3_0 = MF(A2[0][2], BE.h, C20);
    f32x4 a3_1 = MF(A2[1][2], BE.h, C21);

    // ---- rebuild FB, FC with h2_new; FC half1 = h3_prev t0 ----
    unsigned fc2 = FD.u[0], fc3 = FD.u[1];
    FB.u[0] = pkr(a2_0[0], a2_0[1]); FB.u[1] = pkr(a2_0[2], a2_0[3]);
    FB.u[2] = pkr(a2_1[0], a2_1[1]); FB.u[3] = pkr(a2_1[2], a2_1[3]);
    FC.u[0] = pkr(a2_2[0], a2_2[1]); FC.u[1] = pkr(a2_2[2], a2_2[3]);
    FC.u[2] = fc2; FC.u[3] = fc3;

    // ---- L2 finish: chunk0 (a2 t0,t1), chunk1 (a2 t2 | h3_prev t0) ----
    a3_0 = MF(A2[0][0], FB.h, a3_0);
    a3_1 = MF(A2[1][0], FB.h, a3_1);
    a3_0 = MF(A2[0][1], FC.h, a3_0);
    a3_1 = MF(A2[1][1], FC.h, a3_1);

    // ---- FD_new = h3 ----
    FD.u[0] = pkr(a3_0[0], a3_0[1]); FD.u[1] = pkr(a3_0[2], a3_0[3]);
    FD.u[2] = pkr(a3_1[0], a3_1[1]); FD.u[3] = pkr(a3_1[2], a3_1[3]);

    // ---- output head: out = Wout . a3 + bout (no relu) ----
    f32x4 ao = MF(A3, FD.h, C3);
    if (q == 0) o2[(size_t)t * NBAT + b0 + c] = make_float2(ao[0], ao[1]);

    xcur = xnxt;
  }
}

extern "C" void kernel_launch(void* const* d_in, const int* in_sizes, int n_in,
                              void* d_out, int out_size, void* d_ws, size_t ws_size,
                              hipStream_t stream) {
  const float* x    = (const float*)d_in[0];
  const float* wih0 = (const float*)d_in[1];
  const float* whh0 = (const float*)d_in[2];
  const float* bih0 = (const float*)d_in[3];
  const float* bhh0 = (const float*)d_in[4];
  const float* wih1 = (const float*)d_in[5];
  const float* whh1 = (const float*)d_in[6];
  const float* bih1 = (const float*)d_in[7];
  const float* bhh1 = (const float*)d_in[8];
  const float* wih2 = (const float*)d_in[9];
  const float* whh2 = (const float*)d_in[10];
  const float* bih2 = (const float*)d_in[11];
  const float* bhh2 = (const float*)d_in[12];
  const float* wout = (const float*)d_in[13];
  const float* bout = (const float*)d_in[14];
  float* out = (float*)d_out;

  rnn3_fused<<<dim3(NBAT / 16), dim3(64), 0, stream>>>(
      x, wih0, whh0, bih0, bhh0, wih1, whh1, bih1, bhh1,
      wih2, whh2, bih2, bhh2, wout, bout, out);
}